// Round 8
// baseline (272.861 us; speedup 1.0000x reference)
//
#include <hip/hip_runtime.h>
#include <math.h>

// ---------------------------------------------------------------------------
// VQ-VAE eval forward.  N=65536 points x K=1024 codes x D=64, fp32 in/out.
// Distances via f16x2 split-precision MFMA (16x16x32_f16), numerics as R2-R7:
//   z = zh + 2^-12 zl', e = eh + 2^-12 el'  (lo pre-scaled by 4096)
//   argmax key m = (zh.eh - esq/2) + 2^-12 (zh.el' + zl'.eh)
// R8: PERSISTENT-LDS codebook quarter + ZERO-BARRIER K-sweep.
//   grid 1024 = 256 point-groups x 4 K-quarters; block = 256 thr (4 waves).
//   Block stages its 256-code quarter (hi+lo, 64KB, XOR-swizzled) ONCE, then
//   each wave sweeps 16 code-tiles x 4 pt-tiles (384 MFMA) with no syncs.
//   Per-point quarter candidates -> d_out scratch; combine + quantize kernels.
// ---------------------------------------------------------------------------

#define QOUT_SZ  4194304            // 16*64*64*64
#define LOSS_OFF QOUT_SZ
#define IDX_OFF  (QOUT_SZ + 1)
#define PERP_OFF (QOUT_SZ + 1 + 65536)

typedef _Float16 f16x8 __attribute__((ext_vector_type(8)));
typedef _Float16 f16x4 __attribute__((ext_vector_type(4)));
typedef float    f32x4 __attribute__((ext_vector_type(4)));

// ws byte offsets (<= 272 KB, same footprint class as R1-R7)
#define WS_EHI   0          // _Float16[65536] (128 KB)
#define WS_ELO   131072     // _Float16[65536] (128 KB)
#define WS_ESQ   262144     // float[1024]  (stores -0.5*||e||^2)
#define WS_HIST  266240     // float[1024]
#define WS_LOSS  270336     // float[256]

__device__ __forceinline__ void gll16(const void* g, void* l) {
    __builtin_amdgcn_global_load_lds(
        (const __attribute__((address_space(1))) void*)g,
        (__attribute__((address_space(3))) void*)l, 16, 0, 0);
}

// ---------------------------------------------------------------------------
// Prep: split-convert embedding, esq[k] = -0.5*||e_k||^2, zero hist. 64 x 256.
// ---------------------------------------------------------------------------
__global__ void vq_pre(const float* __restrict__ emb,
                       _Float16* __restrict__ ehi, _Float16* __restrict__ elo,
                       float* __restrict__ esq, float* __restrict__ hist) {
    const int t = threadIdx.x;
    const int g = blockIdx.x * 256 + t;          // float4 unit 0..16383
    float4 v = ((const float4*)emb)[g];
    float xs[4] = {v.x, v.y, v.z, v.w};
    f16x4 hi, lo;
    float ss = 0.f;
#pragma unroll
    for (int j = 0; j < 4; ++j) {
        _Float16 h = (_Float16)xs[j];
        hi[j] = h;
        lo[j] = (_Float16)((xs[j] - (float)h) * 4096.0f);
        ss = fmaf(xs[j], xs[j], ss);
    }
    ((f16x4*)ehi)[g] = hi;
    ((f16x4*)elo)[g] = lo;
    ss += __shfl_xor(ss, 1, 64);
    ss += __shfl_xor(ss, 2, 64);
    ss += __shfl_xor(ss, 4, 64);
    ss += __shfl_xor(ss, 8, 64);
    if ((t & 15) == 0) esq[g >> 4] = -0.5f * ss;
    if (blockIdx.x < 4) hist[blockIdx.x * 256 + t] = 0.f;
}

// ---------------------------------------------------------------------------
// Distance+argmin over one codebook QUARTER. 1024 blocks x 256 thr (4 waves).
// blk = pg*4 + kq. Block owns 256 points (4 bh rows, one per wave) and codes
// [kq*256, kq*256+256). Stage quarter once -> barrier -> barrier-free sweep.
// Candidates (best val, idx) per (point, quarter) -> out[0 .. 2MB) scratch.
// ---------------------------------------------------------------------------
__launch_bounds__(256, 2)
__global__ void vq_dist(const float* __restrict__ z,
                        const _Float16* __restrict__ gehi,
                        const _Float16* __restrict__ gelo,
                        const float* __restrict__ gesq,
                        float* __restrict__ out) {
    __shared__ __align__(16) char eshi[32768];    // [256 codes][128 B] swz
    __shared__ __align__(16) char eslo[32768];
    __shared__ float esql[256];                   // -esq/2 for this quarter

    const int tid  = threadIdx.x;
    const int blk  = blockIdx.x;
    const int pg   = blk >> 2;                    // 0..255 point group
    const int kq   = blk & 3;                     // codebook quarter
    const int lane = tid & 63;
    const int wv   = tid >> 6;                    // 0..3
    const int col  = lane & 15;                   // point row / B col
    const int g    = lane >> 4;                   // 0..3 K-slice quad

    // ---- stage quarter esq ----
    if (tid < 256) esql[tid] = gesq[kq * 256 + tid];

    // ---- stage codebook quarter via global_load_lds (linear dest,
    //      pre-XOR-swizzled source; mapping verified conflict-free R4-R7) ----
    const char* gh = (const char*)gehi + (size_t)kq * 32768;
    const char* gl = (const char*)gelo + (size_t)kq * 32768;
#pragma unroll
    for (int i = 0; i < 8; ++i) {
        const int u  = tid + 256 * i;             // 16B unit 0..2047
        const int c  = u >> 3;                    // code 0..255
        const size_t so = (size_t)c * 128 + (size_t)(((u & 7) ^ (c & 7)) << 4);
        gll16(gh + so, eshi + i * 4096 + wv * 1024);
        gll16(gl + so, eslo + i * 4096 + wv * 1024);
    }

    // ---- A fragments from global (overlaps staging DMA) ----
    const int bh = pg * 4 + wv;                   // global (b,h) row
    const int b  = bh >> 6;
    const int h  = bh & 63;
    const float* zrow = z + (size_t)b * 262144 + (size_t)h * 64 + col;
    f16x8 Ah[4][2], Al[4][2];
#pragma unroll
    for (int pt = 0; pt < 4; ++pt) {
#pragma unroll
        for (int m = 0; m < 2; ++m) {
#pragma unroll
            for (int j = 0; j < 8; ++j) {
                int c = m * 32 + g * 8 + j;
                float x = zrow[pt * 16 + (size_t)c * 4096];
                _Float16 hh = (_Float16)x;
                Ah[pt][m][j] = hh;
                Al[pt][m][j] = (_Float16)((x - (float)hh) * 4096.0f);
            }
        }
    }

    asm volatile("s_waitcnt vmcnt(0)" ::: "memory");
    __syncthreads();                              // codebook + esql resident

    // ---- per-lane invariant LDS byte offsets (swizzled) ----
    const int inv0 = col * 128 + (((0 + g) ^ (col & 7)) << 4);   // m=0
    const int inv1 = col * 128 + (((4 + g) ^ (col & 7)) << 4);   // m=1

    float best[4][4];
    int   besti[4][4];
#pragma unroll
    for (int pt = 0; pt < 4; ++pt)
#pragma unroll
        for (int r = 0; r < 4; ++r) { best[pt][r] = -3.4e38f; besti[pt][r] = 0; }

#define LDB(BH0, BH1, BL0, BL1, E2, ct) do {                              \
        const int o_ = (ct) * 2048;                                       \
        BH0 = *(const f16x8*)(eshi + o_ + inv0);                          \
        BH1 = *(const f16x8*)(eshi + o_ + inv1);                          \
        BL0 = *(const f16x8*)(eslo + o_ + inv0);                          \
        BL1 = *(const f16x8*)(eslo + o_ + inv1);                          \
        E2  = esql[(ct) * 16 + col];                                      \
    } while (0)

#define CMP(BH0, BH1, BL0, BL1, E2, ct) do {                              \
        const int kidx_ = kq * 256 + (ct) * 16 + col;                     \
        _Pragma("unroll")                                                  \
        for (int pt_ = 0; pt_ < 4; ++pt_) {                                \
            f32x4 ah_ = {E2, E2, E2, E2};                                  \
            f32x4 ax_ = {0.f, 0.f, 0.f, 0.f};                              \
            ah_ = __builtin_amdgcn_mfma_f32_16x16x32_f16(Ah[pt_][0], BH0, ah_, 0, 0, 0); \
            ah_ = __builtin_amdgcn_mfma_f32_16x16x32_f16(Ah[pt_][1], BH1, ah_, 0, 0, 0); \
            ax_ = __builtin_amdgcn_mfma_f32_16x16x32_f16(Ah[pt_][0], BL0, ax_, 0, 0, 0); \
            ax_ = __builtin_amdgcn_mfma_f32_16x16x32_f16(Ah[pt_][1], BL1, ax_, 0, 0, 0); \
            ax_ = __builtin_amdgcn_mfma_f32_16x16x32_f16(Al[pt_][0], BH0, ax_, 0, 0, 0); \
            ax_ = __builtin_amdgcn_mfma_f32_16x16x32_f16(Al[pt_][1], BH1, ax_, 0, 0, 0); \
            _Pragma("unroll")                                              \
            for (int r_ = 0; r_ < 4; ++r_) {                               \
                float mv_ = fmaf(0x1p-12f, ax_[r_], ah_[r_]);              \
                if (mv_ > best[pt_][r_]) {                                 \
                    best[pt_][r_] = mv_; besti[pt_][r_] = kidx_;           \
                }                                                          \
            }                                                              \
        }                                                                  \
    } while (0)

    // ---- barrier-free sweep: 16 code-tiles, reg ping-pong (named bufs) ----
    f16x8 Xh0, Xh1, Xl0, Xl1, Yh0, Yh1, Yl0, Yl1;
    float EX, EY;
    LDB(Xh0, Xh1, Xl0, Xl1, EX, 0);
#pragma unroll
    for (int ct = 0; ct < 14; ct += 2) {
        LDB(Yh0, Yh1, Yl0, Yl1, EY, ct + 1);
        CMP(Xh0, Xh1, Xl0, Xl1, EX, ct);
        LDB(Xh0, Xh1, Xl0, Xl1, EX, ct + 2);
        CMP(Yh0, Yh1, Yl0, Yl1, EY, ct + 1);
    }
    LDB(Yh0, Yh1, Yl0, Yl1, EY, 15);
    CMP(Xh0, Xh1, Xl0, Xl1, EX, 14);
    CMP(Yh0, Yh1, Yl0, Yl1, EY, 15);
#undef LDB
#undef CMP

    // ---- in-wave argmin over the 16 code cols (np first-min tie-break) ----
#pragma unroll
    for (int mask = 1; mask <= 8; mask <<= 1) {
#pragma unroll
        for (int pt = 0; pt < 4; ++pt)
#pragma unroll
            for (int r = 0; r < 4; ++r) {
                float ov = __shfl_xor(best[pt][r], mask, 64);
                int   oi = __shfl_xor(besti[pt][r], mask, 64);
                if (ov > best[pt][r] ||
                    (ov == best[pt][r] && oi < besti[pt][r])) {
                    best[pt][r] = ov; besti[pt][r] = oi;
                }
            }
    }

    // ---- write quarter candidates to out[0..2MB) scratch (float2) ----
    if (col == 0) {                               // lanes 0,16,32,48
        float2* cand = (float2*)out;
        const int pbase = pg * 256 + wv * 64;
#pragma unroll
        for (int pt = 0; pt < 4; ++pt)
#pragma unroll
            for (int r = 0; r < 4; ++r) {
                int p = pbase + pt * 16 + g * 4 + r;
                float2 cv; cv.x = best[pt][r]; cv.y = (float)besti[pt][r];
                cand[p * 4 + kq] = cv;
            }
    }
}

// ---------------------------------------------------------------------------
// Combine 4 quarter-candidates per point -> final index + histogram.
// Reads out[0..2MB) scratch, writes out[IDX..] (disjoint). 256 x 256.
// ---------------------------------------------------------------------------
__global__ void vq_comb(float* __restrict__ out, float* __restrict__ hist) {
    const int p = blockIdx.x * 256 + threadIdx.x;
    const float4* cand4 = (const float4*)out;     // (v0,i0,v1,i1),(v2,i2,v3,i3)
    float4 c01 = cand4[p * 2];
    float4 c23 = cand4[p * 2 + 1];
    float bv = c01.x; float bi = c01.y;
    if (c01.z > bv) { bv = c01.z; bi = c01.w; }   // ascending kq: strict >
    if (c23.x > bv) { bv = c23.x; bi = c23.y; }
    if (c23.z > bv) { bv = c23.z; bi = c23.w; }
    out[(size_t)IDX_OFF + p] = bi;
    atomicAdd(&hist[(int)bi], 1.0f);              // exact int counts
}

// ---------------------------------------------------------------------------
// Quantize + loss partials. Overwrites the whole quantized region (incl. the
// candidate scratch). Reads idx from out[IDX..] (disjoint from writes). 256x256.
// ---------------------------------------------------------------------------
__global__ void vq_quant(const float* __restrict__ z,
                         const float* __restrict__ emb,
                         float* __restrict__ out,
                         float* __restrict__ lossp) {
    __shared__ float redw[4];
    const int tid = threadIdx.x;
    const int p   = blockIdx.x * 256 + tid;
    const int lane = tid & 63;
    const int wv   = tid >> 6;

    const int idx = (int)out[(size_t)IDX_OFF + p];
    const int b = p >> 12;
    const int h = (p >> 6) & 63;
    const int w = p & 63;
    const float* ev = emb + (size_t)idx * 64;
    const float* zr = z   + (size_t)b * 262144 + (size_t)h * 64 + w;
    float*     outq = out + (size_t)b * 262144 + (size_t)h * 64 + w;

    float lsum = 0.f;
#pragma unroll
    for (int i = 0; i < 16; ++i) {
        float4 qv = *(const float4*)(ev + i * 4);
        float q4[4] = {qv.x, qv.y, qv.z, qv.w};
#pragma unroll
        for (int jj = 0; jj < 4; ++jj) {
            int c = i * 4 + jj;
            float zv = zr[(size_t)c * 4096];
            outq[(size_t)c * 4096] = q4[jj];
            float d = q4[jj] - zv;
            lsum = fmaf(d, d, lsum);
        }
    }
#pragma unroll
    for (int off = 32; off > 0; off >>= 1)
        lsum += __shfl_xor(lsum, off, 64);
    if (lane == 0) redw[wv] = lsum;
    __syncthreads();
    if (tid == 0)
        lossp[blockIdx.x] = redw[0] + redw[1] + redw[2] + redw[3];
}

// ---------------------------------------------------------------------------
// Finalize: loss + perplexity, fixed-order tree. 1 x 1024.
// ---------------------------------------------------------------------------
__global__ void vq_fin(const float* __restrict__ hist,
                       const float* __restrict__ lossp,
                       float* __restrict__ out) {
    __shared__ float sh[1024];
    __shared__ float sl[1024];
    int t = threadIdx.x;
    float hc = hist[t];
    float p  = hc * (1.0f / 65536.0f);
    sh[t] = p * logf(p + 1e-10f);
    sl[t] = (t < 256) ? lossp[t] : 0.f;
    __syncthreads();
    for (int s = 512; s > 0; s >>= 1) {
        if (t < s) { sh[t] += sh[t + s]; sl[t] += sl[t + s]; }
        __syncthreads();
    }
    if (t == 0) {
        out[LOSS_OFF] = 0.25f * sl[0] / (float)QOUT_SZ;
        out[PERP_OFF] = expf(-sh[0]);
    }
}

extern "C" void kernel_launch(void* const* d_in, const int* in_sizes, int n_in,
                              void* d_out, int out_size, void* d_ws, size_t ws_size,
                              hipStream_t stream) {
    const float* z   = (const float*)d_in[0];   // [16,64,64,64] fp32 NCHW
    const float* emb = (const float*)d_in[1];   // [1024,64] fp32
    float* out = (float*)d_out;
    char*  ws  = (char*)d_ws;

    _Float16* ehi   = (_Float16*)(ws + WS_EHI);
    _Float16* elo   = (_Float16*)(ws + WS_ELO);
    float*    esq   = (float*)(ws + WS_ESQ);
    float*    hist  = (float*)(ws + WS_HIST);
    float*    lossp = (float*)(ws + WS_LOSS);

    vq_pre<<<64, 256, 0, stream>>>(emb, ehi, elo, esq, hist);
    vq_dist<<<1024, 256, 0, stream>>>(z, ehi, elo, esq, out);
    vq_comb<<<256, 256, 0, stream>>>(out, hist);
    vq_quant<<<256, 256, 0, stream>>>(z, emb, out, lossp);
    vq_fin<<<1, 1024, 0, stream>>>(hist, lossp, out);
}

// Round 9
// 67.227 us; speedup vs baseline: 4.0588x; 4.0588x over previous
//
#include <hip/hip_runtime.h>
#include <math.h>

// ---------------------------------------------------------------------------
// VQ-VAE eval forward.  N=65536 points x K=1024 codes x D=64, fp32 in/out.
// Distances via f16x2 split-precision MFMA (16x16x32_f16), numerics as R2-R8:
//   z = zh + 2^-12 zl', e = eh + 2^-12 el'  (lo pre-scaled by 4096)
//   argmax key m = (zh.eh - esq/2) + 2^-12 (zh.el' + zl'.eh)
// R9: ILP-first. 1024 blocks x 128 thr (2 waves), launch_bounds(128,2):
//   4 blocks/CU (grid fully resident), 2 waves/SIMD, 256-VGPR budget.
//   Wave owns 32 points and sweeps ALL 64 codes/chunk (48 MFMA, 8 independent
//   tile-acc groups in flight; ax split into two 2-deep chains). In-wave
//   butterfly gives FINAL argmin (no cross-wave combine). 2-buf staging,
//   verified-conflict-free XOR swizzle, vmcnt(0)+barrier per chunk (2-wave
//   barrier groups).
// ---------------------------------------------------------------------------

#define QOUT_SZ  4194304            // 16*64*64*64
#define LOSS_OFF QOUT_SZ
#define IDX_OFF  (QOUT_SZ + 1)
#define PERP_OFF (QOUT_SZ + 1 + 65536)

typedef _Float16 f16x8 __attribute__((ext_vector_type(8)));
typedef _Float16 f16x4 __attribute__((ext_vector_type(4)));
typedef float    f32x4 __attribute__((ext_vector_type(4)));

// ws byte offsets
#define WS_EHI   0          // _Float16[65536] (128 KB)
#define WS_ELO   131072     // _Float16[65536] (128 KB)
#define WS_ESQ   262144     // float[1024]  (stores -0.5*||e||^2)
#define WS_HIST  266240     // float[1024]
#define WS_LOSS  270336     // float[1024]

__device__ __forceinline__ void gll16(const void* g, void* l) {
    __builtin_amdgcn_global_load_lds(
        (const __attribute__((address_space(1))) void*)g,
        (__attribute__((address_space(3))) void*)l, 16, 0, 0);
}

// ---------------------------------------------------------------------------
// Prep: split-convert embedding, esq[k] = -0.5*||e_k||^2, zero hist. 64 x 256.
// ---------------------------------------------------------------------------
__global__ void vq_pre(const float* __restrict__ emb,
                       _Float16* __restrict__ ehi, _Float16* __restrict__ elo,
                       float* __restrict__ esq, float* __restrict__ hist) {
    const int t = threadIdx.x;
    const int g = blockIdx.x * 256 + t;          // float4 unit 0..16383
    float4 v = ((const float4*)emb)[g];
    float xs[4] = {v.x, v.y, v.z, v.w};
    f16x4 hi, lo;
    float ss = 0.f;
#pragma unroll
    for (int j = 0; j < 4; ++j) {
        _Float16 h = (_Float16)xs[j];
        hi[j] = h;
        lo[j] = (_Float16)((xs[j] - (float)h) * 4096.0f);
        ss = fmaf(xs[j], xs[j], ss);
    }
    ((f16x4*)ehi)[g] = hi;
    ((f16x4*)elo)[g] = lo;
    ss += __shfl_xor(ss, 1, 64);
    ss += __shfl_xor(ss, 2, 64);
    ss += __shfl_xor(ss, 4, 64);
    ss += __shfl_xor(ss, 8, 64);
    if ((t & 15) == 0) esq[g >> 4] = -0.5f * ss;
    if (blockIdx.x < 4) hist[blockIdx.x * 256 + t] = 0.f;
}

// ---------------------------------------------------------------------------
// Main. 1024 blocks x 128 threads (2 waves). Block owns 64 points (1 bh row);
// wave wv owns points wv*32..wv*32+31 (2 pt-tiles) and sweeps all codes.
// 16 chunks of 64 codes, 2-buffered LDS staging.
// ---------------------------------------------------------------------------
__launch_bounds__(128, 2)
__global__ void vq_main(const float* __restrict__ z,
                        const float* __restrict__ emb,
                        const _Float16* __restrict__ gehi,
                        const _Float16* __restrict__ gelo,
                        const float* __restrict__ gesq,
                        float* __restrict__ hist,
                        float* __restrict__ lossp,
                        float* __restrict__ out) {
    __shared__ __align__(16) char es[32768];   // 2 bufs x (hi 8K | lo 8K)
    __shared__ float esql[1024];               // -esq/2
    __shared__ int   idxs[64];
    __shared__ float redw[2];

    const int tid  = threadIdx.x;              // 0..127
    const int blk  = blockIdx.x;               // = b*64 + h
    const int b    = blk >> 6;
    const int h    = blk & 63;
    const int lane = tid & 63;
    const int wv   = tid >> 6;                 // 0..1
    const int col  = lane & 15;                // point row / code col
    const int g    = lane >> 4;                // 0..3 K-slice quad

    // ---- stage -esq/2 into LDS (coalesced, once) ----
#pragma unroll
    for (int i = 0; i < 8; ++i) esql[tid + 128 * i] = gesq[tid + 128 * i];

    // ---- staging geometry (verified conflict-free swizzle, R4-R7) ----
    // chunk = 64 codes x 128 B per plane = 512 16B-units; 4 hi + 4 lo / thread.
    const char* gh = (const char*)gehi;
    const char* gl = (const char*)gelo;
    size_t so[4];
#pragma unroll
    for (int i = 0; i < 4; ++i) {
        int u = tid + 128 * i;                 // unit 0..511
        int c = u >> 3;                        // code 0..63
        so[i] = (size_t)c * 128 + (size_t)(((u & 7) ^ (c & 7)) << 4);
    }
    // wave-uniform LDS dest bases: hi byte u*16 = (i*2048 + wv*1024) + lane*16
#define STAGE(n, bo) do {                                                 \
        const size_t gb_ = (size_t)(n) * 8192;                            \
        gll16(gh + gb_ + so[0], es + (bo) + 0 * 2048 + wv * 1024);        \
        gll16(gh + gb_ + so[1], es + (bo) + 1 * 2048 + wv * 1024);        \
        gll16(gh + gb_ + so[2], es + (bo) + 2 * 2048 + wv * 1024);        \
        gll16(gh + gb_ + so[3], es + (bo) + 3 * 2048 + wv * 1024);        \
        gll16(gl + gb_ + so[0], es + (bo) + 8192 + 0 * 2048 + wv * 1024); \
        gll16(gl + gb_ + so[1], es + (bo) + 8192 + 1 * 2048 + wv * 1024); \
        gll16(gl + gb_ + so[2], es + (bo) + 8192 + 2 * 2048 + wv * 1024); \
        gll16(gl + gb_ + so[3], es + (bo) + 8192 + 3 * 2048 + wv * 1024); \
    } while (0)

    STAGE(0, 0);                               // chunk 0 in flight

    // ---- A fragments straight from global (overlaps chunk-0 DMA) ----
    const float* zb = z + (size_t)b * 262144 + (size_t)h * 64;
    const float* zrw = zb + wv * 32 + col;
    f16x8 Ah[2][2], Al[2][2];
#pragma unroll
    for (int pt = 0; pt < 2; ++pt) {
#pragma unroll
        for (int m = 0; m < 2; ++m) {
#pragma unroll
            for (int j = 0; j < 8; ++j) {
                int c = m * 32 + g * 8 + j;
                float x = zrw[pt * 16 + (size_t)c * 4096];
                _Float16 hh = (_Float16)x;
                Ah[pt][m][j] = hh;
                Al[pt][m][j] = (_Float16)((x - (float)hh) * 4096.0f);
            }
        }
    }

    // ---- per-lane B read offsets (swizzled; ct*16 ≡ 0 mod 8 -> col&7) ----
    int rb[4][2];
#pragma unroll
    for (int ct = 0; ct < 4; ++ct) {
        int cl = ct * 16 + col;
#pragma unroll
        for (int m = 0; m < 2; ++m)
            rb[ct][m] = cl * 128 + ((((m << 2) + g) ^ (col & 7)) << 4);
    }

    float best[2][4];
    int   besti[2][4];
#pragma unroll
    for (int pt = 0; pt < 2; ++pt)
#pragma unroll
        for (int r = 0; r < 4; ++r) { best[pt][r] = -3.4e38f; besti[pt][r] = 0; }

    // ---- k loop: 16 chunks of 64 codes, 2-buffered ----
    for (int sc = 0; sc < 16; ++sc) {
        asm volatile("s_waitcnt vmcnt(0)" ::: "memory");
        __builtin_amdgcn_s_barrier();
        asm volatile("" ::: "memory");
        const int bo = (sc & 1) * 16384;
        if (sc < 15) STAGE(sc + 1, bo ^ 16384);

        const char* bp = es + bo;
        const int kb = sc * 64;
#pragma unroll
        for (int ct = 0; ct < 4; ++ct) {
            const int  kcol = kb + ct * 16 + col;
            const float e2  = esql[kcol];
            f16x8 Bh0 = *(const f16x8*)(bp + rb[ct][0]);
            f16x8 Bh1 = *(const f16x8*)(bp + rb[ct][1]);
            f16x8 Bl0 = *(const f16x8*)(bp + 8192 + rb[ct][0]);
            f16x8 Bl1 = *(const f16x8*)(bp + 8192 + rb[ct][1]);
#pragma unroll
            for (int pt = 0; pt < 2; ++pt) {
                f32x4 ah  = {e2, e2, e2, e2};
                f32x4 ax1 = {0.f, 0.f, 0.f, 0.f};
                f32x4 ax2 = {0.f, 0.f, 0.f, 0.f};
                ah  = __builtin_amdgcn_mfma_f32_16x16x32_f16(Ah[pt][0], Bh0, ah,  0, 0, 0);
                ah  = __builtin_amdgcn_mfma_f32_16x16x32_f16(Ah[pt][1], Bh1, ah,  0, 0, 0);
                ax1 = __builtin_amdgcn_mfma_f32_16x16x32_f16(Ah[pt][0], Bl0, ax1, 0, 0, 0);
                ax1 = __builtin_amdgcn_mfma_f32_16x16x32_f16(Ah[pt][1], Bl1, ax1, 0, 0, 0);
                ax2 = __builtin_amdgcn_mfma_f32_16x16x32_f16(Al[pt][0], Bh0, ax2, 0, 0, 0);
                ax2 = __builtin_amdgcn_mfma_f32_16x16x32_f16(Al[pt][1], Bh1, ax2, 0, 0, 0);
#pragma unroll
                for (int r = 0; r < 4; ++r) {
                    float mval = fmaf(0x1p-12f, ax1[r] + ax2[r], ah[r]);
                    if (mval > best[pt][r]) { best[pt][r] = mval; besti[pt][r] = kcol; }
                }
            }
        }
    }
#undef STAGE

    // ---- in-wave argmin over 16 code-cols = FINAL (np first-min tie-break) ----
#pragma unroll
    for (int mask = 1; mask <= 8; mask <<= 1) {
#pragma unroll
        for (int pt = 0; pt < 2; ++pt)
#pragma unroll
            for (int r = 0; r < 4; ++r) {
                float ov = __shfl_xor(best[pt][r], mask, 64);
                int   oi = __shfl_xor(besti[pt][r], mask, 64);
                if (ov > best[pt][r] ||
                    (ov == best[pt][r] && oi < besti[pt][r])) {
                    best[pt][r] = ov; besti[pt][r] = oi;
                }
            }
    }
    if (col == 0) {                            // lanes 0,16,32,48
#pragma unroll
        for (int pt = 0; pt < 2; ++pt)
#pragma unroll
            for (int r = 0; r < 4; ++r)
                idxs[wv * 32 + pt * 16 + g * 4 + r] = besti[pt][r];
    }
    __syncthreads();

    // ---- indices out + histogram ----
    if (tid < 64) {
        int bi = idxs[tid];
        atomicAdd(&hist[bi], 1.0f);            // exact int counts
        out[(size_t)IDX_OFF + blk * 64 + tid] = (float)bi;
    }

    // ---- epilogue: quantized write (coalesced over w) + loss partial ----
    const int w  = tid & 63;
    const int idx = idxs[w];
    const float* ev = emb + (size_t)idx * 64 + wv * 32;
    const float* zr = zb + w;
    float* outq = out + (size_t)b * 262144 + (size_t)h * 64 + w;
    float lsum = 0.f;
#pragma unroll
    for (int i = 0; i < 8; ++i) {
        float4 qv = *(const float4*)(ev + i * 4);
        float q4[4] = {qv.x, qv.y, qv.z, qv.w};
#pragma unroll
        for (int jj = 0; jj < 4; ++jj) {
            int c = wv * 32 + i * 4 + jj;
            float zv = zr[(size_t)c * 4096];   // L3-hot re-read
            outq[(size_t)c * 4096] = q4[jj];
            float d = q4[jj] - zv;
            lsum = fmaf(d, d, lsum);
        }
    }
#pragma unroll
    for (int off = 32; off > 0; off >>= 1)
        lsum += __shfl_xor(lsum, off, 64);
    if (lane == 0) redw[wv] = lsum;
    __syncthreads();
    if (tid == 0)
        lossp[blk] = redw[0] + redw[1];
}

// ---------------------------------------------------------------------------
// Finalize: loss + perplexity, fixed-order tree. 1 x 1024.
// ---------------------------------------------------------------------------
__global__ void vq_fin(const float* __restrict__ hist,
                       const float* __restrict__ lossp,
                       float* __restrict__ out) {
    __shared__ float sh[1024];
    __shared__ float sl[1024];
    int t = threadIdx.x;
    float hc = hist[t];
    float p  = hc * (1.0f / 65536.0f);
    sh[t] = p * logf(p + 1e-10f);
    sl[t] = lossp[t];
    __syncthreads();
    for (int s = 512; s > 0; s >>= 1) {
        if (t < s) { sh[t] += sh[t + s]; sl[t] += sl[t + s]; }
        __syncthreads();
    }
    if (t == 0) {
        out[LOSS_OFF] = 0.25f * sl[0] / (float)QOUT_SZ;
        out[PERP_OFF] = expf(-sh[0]);
    }
}

extern "C" void kernel_launch(void* const* d_in, const int* in_sizes, int n_in,
                              void* d_out, int out_size, void* d_ws, size_t ws_size,
                              hipStream_t stream) {
    const float* z   = (const float*)d_in[0];   // [16,64,64,64] fp32 NCHW
    const float* emb = (const float*)d_in[1];   // [1024,64] fp32
    float* out = (float*)d_out;
    char*  ws  = (char*)d_ws;

    _Float16* ehi   = (_Float16*)(ws + WS_EHI);
    _Float16* elo   = (_Float16*)(ws + WS_ELO);
    float*    esq   = (float*)(ws + WS_ESQ);
    float*    hist  = (float*)(ws + WS_HIST);
    float*    lossp = (float*)(ws + WS_LOSS);

    vq_pre<<<64, 256, 0, stream>>>(emb, ehi, elo, esq, hist);
    vq_main<<<1024, 128, 0, stream>>>(z, emb, ehi, elo, esq, hist, lossp, out);
    vq_fin<<<1, 1024, 0, stream>>>(hist, lossp, out);
}